// Round 5
// baseline (202.869 us; speedup 1.0000x reference)
//
#include <hip/hip_runtime.h>

// 3-NN IDW upsampling, round 5: exact spatial-grid kNN.
// Pipeline (all tiny kernels, graph-captured, all on `stream`):
//   memset(counters) -> k_hist -> k_scan (prefix) -> k_scatter -> k_query
// k_query: per-lane Chebyshev-ring expansion over a 16^3 grid with a
// conservative prune bound; top-8 packed-key candidates (validated med3
// chain) -> exact-f64 re-rank + f64 IDW weights (bit-identical epilogue to
// rounds 1-4, absmax 0.00390625).

constexpr int   B   = 2;
constexpr int   S   = 4096;
constexpr int   NQ  = 16384;
constexpr int   G   = 16;
constexpr int   NC  = G * G * G;          // 4096 cells
constexpr float LOF  = -4.25f;
constexpr float W    = 0.53125f;          // 8.5 / 16
constexpr float INVW = 1.0f / W;

// workspace byte offsets (total ~459 KB)
constexpr size_t OFF_SCNT = 0;            // u32[2][4096]   (memset [0, 65536))
constexpr size_t OFF_DCNT = 32768;        // u32[2][4096]
constexpr size_t OFF_SPFX = 65536;        // u32[2][4097]   pad to 32800 B
constexpr size_t OFF_DPFX = 98336;        // u32[2][4097]
constexpr size_t OFF_SCUR = 131136;       // u32[2][4096]
constexpr size_t OFF_DCUR = 163904;       // u32[2][4096]
constexpr size_t OFF_SSRT = 196672;       // float4[2][4096] (16B aligned)
constexpr size_t OFF_DSRT = 327744;       // u32[2][16384]

__device__ __forceinline__ unsigned med3u(unsigned a, unsigned b, unsigned c) {
    unsigned d;
    asm("v_med3_u32 %0, %1, %2, %3" : "=v"(d) : "v"(a), "v"(b), "v"(c));
    return d;
}

__device__ __forceinline__ int cell1(float v) {
    int c = (int)floorf((v - LOF) * INVW);
    return min(max(c, 0), G - 1);
}

// ---------------- histogram: sparse + dense point counts per cell ----------
__global__ __launch_bounds__(256)
void k_hist(const float* __restrict__ sxyz, const float* __restrict__ xyz,
            unsigned* __restrict__ ws32)
{
    const int i = blockIdx.x * 256 + threadIdx.x;
    unsigned* scnt = ws32 + OFF_SCNT / 4;
    unsigned* dcnt = ws32 + OFF_DCNT / 4;
    if (i < B * S) {
        const int b = i / S, p = i % S;
        const float* base = sxyz + (size_t)b * 3 * S;
        const float x = base[p], y = base[p + S], z = base[p + 2 * S];
        const int ci = (cell1(z) * G + cell1(y)) * G + cell1(x);
        atomicAdd(&scnt[b * NC + ci], 1u);
    } else {
        const int k = i - B * S;
        const int b = k / NQ, p = k % NQ;
        const float* base = xyz + (size_t)b * 3 * NQ;
        const float x = base[p], y = base[p + NQ], z = base[p + 2 * NQ];
        const int ci = (cell1(z) * G + cell1(y)) * G + cell1(x);
        atomicAdd(&dcnt[b * NC + ci], 1u);
    }
}

// ---------------- exclusive prefix sums (4 scans of 4096, one block) -------
__global__ __launch_bounds__(1024)
void k_scan(unsigned* __restrict__ ws32)
{
    __shared__ unsigned part[1024];
    const int t = threadIdx.x;
    for (int a = 0; a < 4; ++a) {
        unsigned *cnt, *pfx, *cur;
        if (a < 2) {
            cnt = ws32 + OFF_SCNT / 4 + a * NC;
            pfx = ws32 + OFF_SPFX / 4 + a * (NC + 1);
            cur = ws32 + OFF_SCUR / 4 + a * NC;
        } else {
            cnt = ws32 + OFF_DCNT / 4 + (a - 2) * NC;
            pfx = ws32 + OFF_DPFX / 4 + (a - 2) * (NC + 1);
            cur = ws32 + OFF_DCUR / 4 + (a - 2) * NC;
        }
        const unsigned v0 = cnt[t * 4 + 0], v1 = cnt[t * 4 + 1];
        const unsigned v2 = cnt[t * 4 + 2], v3 = cnt[t * 4 + 3];
        part[t] = v0 + v1 + v2 + v3;
        __syncthreads();
        for (int s = 1; s < 1024; s <<= 1) {
            const unsigned add = (t >= s) ? part[t - s] : 0u;
            __syncthreads();
            part[t] += add;
            __syncthreads();
        }
        unsigned run = (t == 0) ? 0u : part[t - 1];
        __syncthreads();   // part[] reused next iteration
        pfx[t * 4 + 0] = run; cur[t * 4 + 0] = run; run += v0;
        pfx[t * 4 + 1] = run; cur[t * 4 + 1] = run; run += v1;
        pfx[t * 4 + 2] = run; cur[t * 4 + 2] = run; run += v2;
        pfx[t * 4 + 3] = run; cur[t * 4 + 3] = run; run += v3;
        if (t == 1023) pfx[NC] = run;
    }
}

// ---------------- scatter into cell-sorted arrays --------------------------
__global__ __launch_bounds__(256)
void k_scatter(const float* __restrict__ sxyz, const float* __restrict__ xyz,
               unsigned* __restrict__ ws32)
{
    const int i = blockIdx.x * 256 + threadIdx.x;
    unsigned* scur = ws32 + OFF_SCUR / 4;
    unsigned* dcur = ws32 + OFF_DCUR / 4;
    float4*   ssrt = reinterpret_cast<float4*>((char*)ws32 + OFF_SSRT);
    unsigned* dsrt = ws32 + OFF_DSRT / 4;
    if (i < B * S) {
        const int b = i / S, p = i % S;
        const float* base = sxyz + (size_t)b * 3 * S;
        const float x = base[p], y = base[p + S], z = base[p + 2 * S];
        const int ci = (cell1(z) * G + cell1(y)) * G + cell1(x);
        const unsigned pos = atomicAdd(&scur[b * NC + ci], 1u);
        ssrt[b * S + pos] = make_float4(x, y, z, __uint_as_float((unsigned)p));
    } else {
        const int k = i - B * S;
        const int b = k / NQ, p = k % NQ;
        const float* base = xyz + (size_t)b * 3 * NQ;
        const float x = base[p], y = base[p + NQ], z = base[p + 2 * NQ];
        const int ci = (cell1(z) * G + cell1(y)) * G + cell1(x);
        const unsigned pos = atomicAdd(&dcur[b * NC + ci], 1u);
        dsrt[b * NQ + pos] = (unsigned)p;
    }
}

// ---------------- query: ring expansion + top-8 + f64 epilogue -------------
__global__ __launch_bounds__(256)
void k_query(const float* __restrict__ xyz, const float* __restrict__ sflow,
             float* __restrict__ out, const unsigned* __restrict__ ws32)
{
    const int b    = blockIdx.y;
    const int slot = blockIdx.x * 256 + threadIdx.x;

    const unsigned* dsrt = ws32 + OFF_DSRT / 4 + b * NQ;
    const unsigned* pfx  = ws32 + OFF_SPFX / 4 + b * (NC + 1);
    const float4*   ssrt = reinterpret_cast<const float4*>((const char*)ws32 + OFF_SSRT) + b * S;

    const unsigned orig = dsrt[slot];
    const float* xb = xyz + (size_t)b * 3 * NQ;
    const float qx = xb[orig], qy = xb[NQ + orig], qz = xb[2 * NQ + orig];

    const int hx = cell1(qx), hy = cell1(qy), hz = cell1(qz);

    // min distance from q to any face of its (clamped) home cell; may be
    // negative for outlier queries -> bound shrinks -> prunes less (safe).
    float mf;
    {
        const float lx = LOF + hx * W, ly = LOF + hy * W, lz = LOF + hz * W;
        const float fx = fminf(qx - lx, lx + W - qx);
        const float fy = fminf(qy - ly, ly + W - qy);
        const float fz = fminf(qz - lz, lz + W - qz);
        mf = fminf(fx, fminf(fy, fz));
    }

    unsigned b0, b1, b2k, b3, b4, b5, b6, b7;
    b0 = b1 = b2k = b3 = b4 = b5 = b6 = b7 = 0xFFFFFFFFu;

    for (int r = 0; r <= G; ++r) {
        if (r > 0) {
            // any point in a cell at Chebyshev radius r is at least this far
            const float db  = fmaxf((float)(r - 1) * W + mf, 0.0f);
            const float bsq = db * db;
            // d3 upper bound: round truncated key up (|0xFFF >= true bits).
            // While <3 real candidates, b2k==0xFFFFFFFF -> NaN -> no prune.
            const float d3f = __uint_as_float(b2k | 0xFFFu) * 1.0001f;
            if (bsq > d3f) break;
        }
        for (int dz = -r; dz <= r; ++dz) {
            const int cz = hz + dz;
            if (cz < 0 || cz >= G) continue;
            for (int dy = -r; dy <= r; ++dy) {
                const int cy = hy + dy;
                if (cy < 0 || cy >= G) continue;
                const bool full = (dz == -r || dz == r || dy == -r || dy == r);
                const int  step = full ? 1 : 2 * r;   // shell cells only
                for (int dx = -r; dx <= r; dx += step) {
                    const int cx = hx + dx;
                    if (cx < 0 || cx >= G) continue;
                    const int ci = (cz * G + cy) * G + cx;
                    const unsigned s0 = pfx[ci], e0 = pfx[ci + 1];
                    for (unsigned j = s0; j < e0; ++j) {
                        const float4 p = ssrt[j];
                        const float dxq = qx - p.x;
                        const float dyq = qy - p.y;
                        const float dzq = qz - p.z;
                        const float d2 = dxq * dxq + dyq * dyq + dzq * dzq;
                        unsigned c = (__float_as_uint(d2) & 0xFFFFF000u) | j;
                        b7 = med3u(b6, b7, c); b6 = med3u(b5, b6, c);
                        b5 = med3u(b4, b5, c); b4 = med3u(b3, b4, c);
                        b3 = med3u(b2k, b3, c); b2k = med3u(b1, b2k, c);
                        b1 = med3u(b0, b1, c); b0 = min(b0, c);
                    }
                }
            }
        }
    }

    // exact-f64 re-rank of up to 8 candidates (identical to rounds 1-4);
    // filler keys (0xFFFFFFFF, impossible for real d2) are skipped.
    const unsigned bkarr[8] = { b0, b1, b2k, b3, b4, b5, b6, b7 };
    double e0 = 1e300, e1 = 1e300, e2 = 1e300;
    int    i0 = 0,     i1 = 0,     i2 = 0;
    #pragma unroll
    for (int c = 0; c < 8; ++c) {
        const unsigned key = bkarr[c];
        if (key == 0xFFFFFFFFu) continue;
        const int j = (int)(key & 0xFFFu);
        const float4 p = ssrt[j];
        const double dx = (double)qx - (double)p.x;
        const double dy = (double)qy - (double)p.y;
        const double dz = (double)qz - (double)p.z;
        const double d2 = dx * dx + dy * dy + dz * dz;
        if (d2 < e2) {
            if (d2 < e1) {
                e2 = e1; i2 = i1;
                if (d2 < e0) { e1 = e0; i1 = i0; e0 = d2; i0 = j; }
                else         { e1 = d2; i1 = j; }
            } else {
                e2 = d2; i2 = j;
            }
        }
    }

    double dist0 = sqrt(e0); dist0 = dist0 > 1e-10 ? dist0 : 1e-10;
    double dist1 = sqrt(e1); dist1 = dist1 > 1e-10 ? dist1 : 1e-10;
    double dist2 = sqrt(e2); dist2 = dist2 > 1e-10 ? dist2 : 1e-10;
    const double inv0 = 1.0 / dist0;
    const double inv1 = 1.0 / dist1;
    const double inv2 = 1.0 / dist2;
    const double wsum = inv0 + inv1 + inv2;

    const unsigned so0 = __float_as_uint(ssrt[i0].w);
    const unsigned so1 = __float_as_uint(ssrt[i1].w);
    const unsigned so2 = __float_as_uint(ssrt[i2].w);

    const float* fb = sflow + (size_t)b * 3 * S;
    float*       ob = out   + (size_t)b * 3 * NQ;
    #pragma unroll
    for (int c = 0; c < 3; ++c) {
        const float* fc = fb + c * S;
        const double o =
            (inv0 * (double)fc[so0] +
             inv1 * (double)fc[so1] +
             inv2 * (double)fc[so2]) / wsum;
        ob[c * NQ + orig] = (float)o;
    }
}

extern "C" void kernel_launch(void* const* d_in, const int* in_sizes, int n_in,
                              void* d_out, int out_size, void* d_ws, size_t ws_size,
                              hipStream_t stream)
{
    const float* xyz  = (const float*)d_in[0];
    const float* sxyz = (const float*)d_in[1];
    const float* sflw = (const float*)d_in[2];
    float*       out  = (float*)d_out;
    unsigned*    ws32 = (unsigned*)d_ws;      // needs ~459 KB of d_ws

    // zero the two counter arrays (re-done every call: deterministic)
    hipMemsetAsync(d_ws, 0, 65536, stream);

    const int nPts = B * S + B * NQ;          // 40960
    k_hist   <<<nPts / 256, 256, 0, stream>>>(sxyz, xyz, ws32);
    k_scan   <<<1, 1024, 0, stream>>>(ws32);
    k_scatter<<<nPts / 256, 256, 0, stream>>>(sxyz, xyz, ws32);

    dim3 qgrid(NQ / 256, B);
    k_query  <<<qgrid, 256, 0, stream>>>(xyz, sflw, out, ws32);
}

// Round 6
// 151.986 us; speedup vs baseline: 1.3348x; 1.3348x over previous
//
#include <hip/hip_runtime.h>

// 3-NN IDW upsampling, round 6: spatial-grid kNN with LDS-resident search.
// Pipeline: memset -> k_hist -> k_scan(grid=4, shfl) -> k_scatter -> k_query.
// k_query: 512 blocks x 64 threads (all co-resident, 2 blocks/CU); each block
// stages the batch's cell-sorted points (3 SoA f32 planes, 48KB) + u16 prefix
// table (8.2KB) into LDS; per-lane ring expansion probes LDS only (~5cyc),
// with empty-row skip. Candidate logic + prune bound + packed-key med3 top-8
// + exact-f64 re-rank + f64 IDW epilogue identical to round 5 (passed,
// absmax 0.00390625).

constexpr int   B   = 2;
constexpr int   S   = 4096;
constexpr int   NQ  = 16384;
constexpr int   G   = 16;
constexpr int   NC  = G * G * G;          // 4096 cells
constexpr float LOF  = -4.25f;
constexpr float W    = 0.53125f;          // 8.5 / 16
constexpr float INVW = 1.0f / W;
constexpr int   QPB  = 64;                // queries per block (1 wave)

// workspace byte offsets (total ~459 KB)
constexpr size_t OFF_SCNT = 0;            // u32[2][4096]   (memset [0, 65536))
constexpr size_t OFF_DCNT = 32768;        // u32[2][4096]
constexpr size_t OFF_SPFX = 65536;        // u32[2][4097]   pad to 32800 B
constexpr size_t OFF_DPFX = 98336;        // u32[2][4097]
constexpr size_t OFF_SCUR = 131136;       // u32[2][4096]
constexpr size_t OFF_DCUR = 163904;       // u32[2][4096]
constexpr size_t OFF_SSRT = 196672;       // float4[2][4096] (16B aligned)
constexpr size_t OFF_DSRT = 327744;       // u32[2][16384]

__device__ __forceinline__ unsigned med3u(unsigned a, unsigned b, unsigned c) {
    unsigned d;
    asm("v_med3_u32 %0, %1, %2, %3" : "=v"(d) : "v"(a), "v"(b), "v"(c));
    return d;
}

__device__ __forceinline__ int cell1(float v) {
    int c = (int)floorf((v - LOF) * INVW);
    return min(max(c, 0), G - 1);
}

// ---------------- histogram: sparse + dense point counts per cell ----------
__global__ __launch_bounds__(256)
void k_hist(const float* __restrict__ sxyz, const float* __restrict__ xyz,
            unsigned* __restrict__ ws32)
{
    const int i = blockIdx.x * 256 + threadIdx.x;
    unsigned* scnt = ws32 + OFF_SCNT / 4;
    unsigned* dcnt = ws32 + OFF_DCNT / 4;
    if (i < B * S) {
        const int b = i / S, p = i % S;
        const float* base = sxyz + (size_t)b * 3 * S;
        const float x = base[p], y = base[p + S], z = base[p + 2 * S];
        const int ci = (cell1(z) * G + cell1(y)) * G + cell1(x);
        atomicAdd(&scnt[b * NC + ci], 1u);
    } else {
        const int k = i - B * S;
        const int b = k / NQ, p = k % NQ;
        const float* base = xyz + (size_t)b * 3 * NQ;
        const float x = base[p], y = base[p + NQ], z = base[p + 2 * NQ];
        const int ci = (cell1(z) * G + cell1(y)) * G + cell1(x);
        atomicAdd(&dcnt[b * NC + ci], 1u);
    }
}

// ---------------- exclusive prefix sums: one block per array, shfl-based ---
__global__ __launch_bounds__(1024)
void k_scan(unsigned* __restrict__ ws32)
{
    const int a = blockIdx.x;   // 0,1: sparse batch 0/1; 2,3: dense batch 0/1
    unsigned *cnt, *pfx, *cur;
    if (a < 2) {
        cnt = ws32 + OFF_SCNT / 4 + a * NC;
        pfx = ws32 + OFF_SPFX / 4 + a * (NC + 1);
        cur = ws32 + OFF_SCUR / 4 + a * NC;
    } else {
        cnt = ws32 + OFF_DCNT / 4 + (a - 2) * NC;
        pfx = ws32 + OFF_DPFX / 4 + (a - 2) * (NC + 1);
        cur = ws32 + OFF_DCUR / 4 + (a - 2) * NC;
    }
    const int t    = threadIdx.x;
    const int lane = t & 63;
    const int w    = t >> 6;                 // 16 waves
    const unsigned v0 = cnt[t * 4 + 0], v1 = cnt[t * 4 + 1];
    const unsigned v2 = cnt[t * 4 + 2], v3 = cnt[t * 4 + 3];
    const unsigned tsum = v0 + v1 + v2 + v3;

    unsigned sc = tsum;                      // inclusive wave scan
    #pragma unroll
    for (int d = 1; d < 64; d <<= 1) {
        const unsigned o = __shfl_up(sc, d, 64);
        if (lane >= d) sc += o;
    }
    __shared__ unsigned wsum[16];
    if (lane == 63) wsum[w] = sc;
    __syncthreads();
    if (w == 0 && lane < 16) {
        unsigned x = wsum[lane];
        #pragma unroll
        for (int d = 1; d < 16; d <<= 1) {
            const unsigned o = __shfl_up(x, d, 64);
            if (lane >= d) x += o;
        }
        wsum[lane] = x;                      // inclusive wave totals
    }
    __syncthreads();
    unsigned base = (w ? wsum[w - 1] : 0u) + (sc - tsum);
    pfx[t * 4 + 0] = base; cur[t * 4 + 0] = base; base += v0;
    pfx[t * 4 + 1] = base; cur[t * 4 + 1] = base; base += v1;
    pfx[t * 4 + 2] = base; cur[t * 4 + 2] = base; base += v2;
    pfx[t * 4 + 3] = base; cur[t * 4 + 3] = base; base += v3;
    if (t == 1023) pfx[NC] = base;
}

// ---------------- scatter into cell-sorted arrays --------------------------
__global__ __launch_bounds__(256)
void k_scatter(const float* __restrict__ sxyz, const float* __restrict__ xyz,
               unsigned* __restrict__ ws32)
{
    const int i = blockIdx.x * 256 + threadIdx.x;
    unsigned* scur = ws32 + OFF_SCUR / 4;
    unsigned* dcur = ws32 + OFF_DCUR / 4;
    float4*   ssrt = reinterpret_cast<float4*>((char*)ws32 + OFF_SSRT);
    unsigned* dsrt = ws32 + OFF_DSRT / 4;
    if (i < B * S) {
        const int b = i / S, p = i % S;
        const float* base = sxyz + (size_t)b * 3 * S;
        const float x = base[p], y = base[p + S], z = base[p + 2 * S];
        const int ci = (cell1(z) * G + cell1(y)) * G + cell1(x);
        const unsigned pos = atomicAdd(&scur[b * NC + ci], 1u);
        ssrt[b * S + pos] = make_float4(x, y, z, __uint_as_float((unsigned)p));
    } else {
        const int k = i - B * S;
        const int b = k / NQ, p = k % NQ;
        const float* base = xyz + (size_t)b * 3 * NQ;
        const float x = base[p], y = base[p + NQ], z = base[p + 2 * NQ];
        const int ci = (cell1(z) * G + cell1(y)) * G + cell1(x);
        const unsigned pos = atomicAdd(&dcur[b * NC + ci], 1u);
        dsrt[b * NQ + pos] = (unsigned)p;
    }
}

// ---------------- query: LDS-resident ring expansion + f64 epilogue --------
__global__ __launch_bounds__(QPB)
void k_query(const float* __restrict__ xyz, const float* __restrict__ sflow,
             float* __restrict__ out, const unsigned* __restrict__ ws32)
{
    __shared__ float px[S], py[S], pz[S];          // 48 KiB
    __shared__ unsigned short pfx16[NC + 2];       // 8.2 KiB

    const int blk  = blockIdx.x;                   // 0..511
    const int b    = blk >> 8;
    const int lane = threadIdx.x;
    const int slot = (blk & 255) * QPB + lane;

    const unsigned* pfxg = ws32 + OFF_SPFX / 4 + b * (NC + 1);
    const unsigned* dsrt = ws32 + OFF_DSRT / 4 + b * NQ;
    const float4*   ssrt = reinterpret_cast<const float4*>((const char*)ws32 + OFF_SSRT) + b * S;

    // ---- stage the whole batch's search structure into LDS ----
    for (int j = lane; j < S; j += QPB) {
        const float4 p = ssrt[j];
        px[j] = p.x; py[j] = p.y; pz[j] = p.z;
    }
    for (int j = lane; j < NC + 1; j += QPB)
        pfx16[j] = (unsigned short)pfxg[j];
    __syncthreads();

    const unsigned orig = dsrt[slot];
    const float* xb = xyz + (size_t)b * 3 * NQ;
    const float qx = xb[orig], qy = xb[NQ + orig], qz = xb[2 * NQ + orig];

    const int hx = cell1(qx), hy = cell1(qy), hz = cell1(qz);

    // min distance from q to any face of its (clamped) home cell; may be
    // negative for outlier queries -> bound shrinks -> prunes less (safe).
    float mf;
    {
        const float lx = LOF + hx * W, ly = LOF + hy * W, lz = LOF + hz * W;
        const float fx = fminf(qx - lx, lx + W - qx);
        const float fy = fminf(qy - ly, ly + W - qy);
        const float fz = fminf(qz - lz, lz + W - qz);
        mf = fminf(fx, fminf(fy, fz));
    }

    unsigned b0, b1, b2k, b3, b4, b5, b6, b7;
    b0 = b1 = b2k = b3 = b4 = b5 = b6 = b7 = 0xFFFFFFFFu;

    for (int r = 0; r <= G; ++r) {
        if (r > 0) {
            const float db  = fmaxf((float)(r - 1) * W + mf, 0.0f);
            const float bsq = db * db;
            // d3 upper bound: truncated key rounded up; NaN while <3 cands.
            const float d3f = __uint_as_float(b2k | 0xFFFu) * 1.0001f;
            if (bsq > d3f) break;
        }
        for (int dz = -r; dz <= r; ++dz) {
            const int cz = hz + dz;
            if (cz < 0 || cz >= G) continue;
            for (int dy = -r; dy <= r; ++dy) {
                const int cy = hy + dy;
                if (cy < 0 || cy >= G) continue;
                const int rowbase = (cz * G + cy) * G;
                if (pfx16[rowbase] == pfx16[rowbase + G]) continue;  // empty row
                const bool full = (dz == -r || dz == r || dy == -r || dy == r);
                const int  step = full ? 1 : 2 * r;   // shell cells only
                for (int dx = -r; dx <= r; dx += step) {
                    const int cx = hx + dx;
                    if (cx < 0 || cx >= G) continue;
                    const int ci = rowbase + cx;
                    const unsigned s0 = pfx16[ci], e0 = pfx16[ci + 1];
                    for (unsigned j = s0; j < e0; ++j) {
                        const float dxq = qx - px[j];
                        const float dyq = qy - py[j];
                        const float dzq = qz - pz[j];
                        const float d2 = dxq * dxq + dyq * dyq + dzq * dzq;
                        unsigned c = (__float_as_uint(d2) & 0xFFFFF000u) | j;
                        b7 = med3u(b6, b7, c); b6 = med3u(b5, b6, c);
                        b5 = med3u(b4, b5, c); b4 = med3u(b3, b4, c);
                        b3 = med3u(b2k, b3, c); b2k = med3u(b1, b2k, c);
                        b1 = med3u(b0, b1, c); b0 = min(b0, c);
                    }
                }
            }
        }
    }

    // exact-f64 re-rank of up to 8 candidates (identical to round 5);
    // filler keys (0xFFFFFFFF) skipped.
    const unsigned bkarr[8] = { b0, b1, b2k, b3, b4, b5, b6, b7 };
    double e0 = 1e300, e1 = 1e300, e2 = 1e300;
    int    i0 = 0,     i1 = 0,     i2 = 0;
    #pragma unroll
    for (int c = 0; c < 8; ++c) {
        const unsigned key = bkarr[c];
        if (key == 0xFFFFFFFFu) continue;
        const int j = (int)(key & 0xFFFu);
        const float4 p = ssrt[j];
        const double dx = (double)qx - (double)p.x;
        const double dy = (double)qy - (double)p.y;
        const double dz = (double)qz - (double)p.z;
        const double d2 = dx * dx + dy * dy + dz * dz;
        if (d2 < e2) {
            if (d2 < e1) {
                e2 = e1; i2 = i1;
                if (d2 < e0) { e1 = e0; i1 = i0; e0 = d2; i0 = j; }
                else         { e1 = d2; i1 = j; }
            } else {
                e2 = d2; i2 = j;
            }
        }
    }

    double dist0 = sqrt(e0); dist0 = dist0 > 1e-10 ? dist0 : 1e-10;
    double dist1 = sqrt(e1); dist1 = dist1 > 1e-10 ? dist1 : 1e-10;
    double dist2 = sqrt(e2); dist2 = dist2 > 1e-10 ? dist2 : 1e-10;
    const double inv0 = 1.0 / dist0;
    const double inv1 = 1.0 / dist1;
    const double inv2 = 1.0 / dist2;
    const double wsum = inv0 + inv1 + inv2;

    const unsigned so0 = __float_as_uint(ssrt[i0].w);
    const unsigned so1 = __float_as_uint(ssrt[i1].w);
    const unsigned so2 = __float_as_uint(ssrt[i2].w);

    const float* fb = sflow + (size_t)b * 3 * S;
    float*       ob = out   + (size_t)b * 3 * NQ;
    #pragma unroll
    for (int c = 0; c < 3; ++c) {
        const float* fc = fb + c * S;
        const double o =
            (inv0 * (double)fc[so0] +
             inv1 * (double)fc[so1] +
             inv2 * (double)fc[so2]) / wsum;
        ob[c * NQ + orig] = (float)o;
    }
}

extern "C" void kernel_launch(void* const* d_in, const int* in_sizes, int n_in,
                              void* d_out, int out_size, void* d_ws, size_t ws_size,
                              hipStream_t stream)
{
    const float* xyz  = (const float*)d_in[0];
    const float* sxyz = (const float*)d_in[1];
    const float* sflw = (const float*)d_in[2];
    float*       out  = (float*)d_out;
    unsigned*    ws32 = (unsigned*)d_ws;      // needs ~459 KB of d_ws

    hipMemsetAsync(d_ws, 0, 65536, stream);   // zero counter arrays

    const int nPts = B * S + B * NQ;          // 40960
    k_hist   <<<nPts / 256, 256, 0, stream>>>(sxyz, xyz, ws32);
    k_scan   <<<4, 1024, 0, stream>>>(ws32);
    k_scatter<<<nPts / 256, 256, 0, stream>>>(sxyz, xyz, ws32);

    const int qblocks = (NQ / QPB) * B;       // 512, all co-resident (2/CU)
    k_query  <<<qblocks, QPB, 0, stream>>>(xyz, sflw, out, ws32);
}